// Round 8
// baseline (89.000 us; speedup 1.0000x reference)
//
#include <hip/hip_runtime.h>

#define HH 128
#define WW 128
#define CCH 128
#define NKD 21
#define RAD 10
#define HPAD 148                 // tgt images per b (hp = h+dy, 0..147)
#define ROWH 40                  // halves per row (32c + 8 pad) = 80B
#define CH_HALVES (148 * ROWH)   // 5920 halves per chunk (148 p-rows)
#define CH_BYTES  (CH_HALVES * 2)        // 11840 B
#define IMG_HALVES (4 * CH_HALVES)       // 23680 halves per (b,hp) = 47360 B

typedef _Float16 f16x8 __attribute__((ext_vector_type(8)));
typedef float    f32x4 __attribute__((ext_vector_type(4)));
typedef __fp16   h2f   __attribute__((ext_vector_type(2)));

union PK { uint4 u; h2f h[4]; };

// ------- kernel 1: pack tgt -> f16 image [hp][chunk(32c)][p(148)][40 halves], zero-padded -------
__global__ __launch_bounds__(256)
void pack_tgt(const float* __restrict__ in, __fp16* __restrict__ img) {
    int n = blockIdx.x;                 // 592: b*148 + i (tgt row = i-10)
    int b = n / HPAD, i = n - b * HPAD;
    int tid = threadIdx.x;
    uint4* gi = (uint4*)(img + (size_t)n * IMG_HALVES);
    if (i < RAD || i > 137) {           // h out of range -> all-zero image (2960 uint4)
        uint4 z = make_uint4(0, 0, 0, 0);
#pragma unroll
        for (int k = 0; k < 11; ++k) gi[k * 256 + tid] = z;
        if (tid < 144) gi[11 * 256 + tid] = z;
        return;
    }
    __shared__ __align__(16) char sraw[4 * CH_BYTES];   // 46.25KB
    {   // zero-fill (covers p<10, p>137 pad rows and the 8-half row tail)
        uint4 z = make_uint4(0, 0, 0, 0);
        uint4* sp = (uint4*)sraw;
#pragma unroll
        for (int k = 0; k < 11; ++k) sp[k * 256 + tid] = z;
        if (tid < 144) sp[11 * 256 + tid] = z;
    }
    __syncthreads();
    const float* tg = in + (size_t)(b * 2 + 1) * CCH * HH * WW + (size_t)(i - RAD) * WW;
    int w = tid & 127, half = tid >> 7;
    int p = w + RAD;                    // 10..137
#pragma unroll
    for (int c2 = 0; c2 < 2; ++c2) {
        int cc = half * 2 + c2;         // chunk 0..3 (32 channels each)
#pragma unroll
        for (int g = 0; g < 4; ++g) {   // slot g = halves c_local g*8..g*8+7
            float v[8];
#pragma unroll
            for (int j = 0; j < 8; ++j)
                v[j] = tg[(size_t)(cc * 32 + g * 8 + j) * (HH * WW) + w];
            PK q;
            q.h[0] = __builtin_amdgcn_cvt_pkrtz(v[0], v[1]);
            q.h[1] = __builtin_amdgcn_cvt_pkrtz(v[2], v[3]);
            q.h[2] = __builtin_amdgcn_cvt_pkrtz(v[4], v[5]);
            q.h[3] = __builtin_amdgcn_cvt_pkrtz(v[6], v[7]);
            *(uint4*)(sraw + (size_t)cc * CH_BYTES + p * 80 + g * 16) = q.u;
        }
    }
    __syncthreads();
    const uint4* si = (const uint4*)sraw;
#pragma unroll
    for (int k = 0; k < 11; ++k) gi[k * 256 + tid] = si[k * 256 + tid];
    if (tid < 144) gi[11 * 256 + tid] = si[11 * 256 + tid];
}

// ---------------- kernel 2: fused src-pack + ring-pipelined banded MFMA ----------------
// acc layout (swapped operands): rows = p, cols = w -> direct predicated global stores.
__global__ __launch_bounds__(256, 2)
void corr_mfma(const float* __restrict__ in, const __fp16* __restrict__ img_tgt,
               float* __restrict__ out) {
    int n = blockIdx.x;                 // 512
    int xcd = n & 7, idx = n >> 3;
    int gl = xcd * 64 + idx;            // h-contiguous per XCD
    int b = gl >> 7, h = gl & 127;

    // [ring 4 x 11840B][s_src 32KB] = 80128B -> 2 blocks/CU
    __shared__ __align__(16) char smem[4 * CH_BYTES + 32768];
    char*   s_ring = smem;
    __fp16* s_src  = (__fp16*)(smem + 4 * CH_BYTES);

    int tid = threadIdx.x;
    int q = tid >> 6, lane = tid & 63, r = lane & 15, g = lane >> 4;

    const __fp16* tgb = img_tgt + (size_t)(b * HPAD) * IMG_HALVES;

    // DMA one chunk t=(dy*4+cc) into ring slot t&3; wave q copies 185 uint4 (3 instrs)
    auto stage = [&](int t) {
        int dyp = t >> 2, ccp = t & 3;
        const uint4* gp = (const uint4*)(tgb + ((size_t)(h + dyp) * 4 + ccp) * CH_HALVES)
                          + q * 185 + lane;
        char* lb = s_ring + (size_t)(t & 3) * CH_BYTES + q * 2960;
        __builtin_amdgcn_global_load_lds(
            (const __attribute__((address_space(1))) void*)gp,
            (__attribute__((address_space(3))) void*)lb, 16, 0, 0);
        __builtin_amdgcn_global_load_lds(
            (const __attribute__((address_space(1))) void*)(gp + 64),
            (__attribute__((address_space(3))) void*)(lb + 1024), 16, 0, 0);
        if (lane < 57)
            __builtin_amdgcn_global_load_lds(
                (const __attribute__((address_space(1))) void*)(gp + 128),
                (__attribute__((address_space(3))) void*)(lb + 2048), 16, 0, 0);
    };

    // prefetch chunks 0,1,2 (oldest in FIFO) while we pack src
    stage(0);
    stage(1);
    stage(2);

    // ---- pack src slice (b,h): fp32 [c][w] -> f16 [w][c] swizzled, x 1/128 ----
    {
        const float* src = in + (size_t)(b * 2) * CCH * HH * WW + (size_t)h * WW;
        const float sc = 1.f / 128.f;
        int w = tid & 127, half = tid >> 7;
#pragma unroll
        for (int t8 = 0; t8 < 8; ++t8) {
            int t = half * 8 + t8;          // c-block 0..15
            float v[8];
#pragma unroll
            for (int j = 0; j < 8; ++j) v[j] = src[(size_t)(t * 8 + j) * (HH * WW) + w] * sc;
            PK qq;
            qq.h[0] = __builtin_amdgcn_cvt_pkrtz(v[0], v[1]);
            qq.h[1] = __builtin_amdgcn_cvt_pkrtz(v[2], v[3]);
            qq.h[2] = __builtin_amdgcn_cvt_pkrtz(v[4], v[5]);
            qq.h[3] = __builtin_amdgcn_cvt_pkrtz(v[6], v[7]);
            int slot = t ^ (w & 7);
            *(uint4*)&s_src[w * 128 + slot * 8] = qq.u;
        }
    }
    __syncthreads();   // compiler drains vmcnt(0) here: chunks 0,1,2 landed

    // ---- B-fragments (src w-tiles) to registers for the whole kernel ----
    f16x8 a[2][4];
#pragma unroll
    for (int wi = 0; wi < 2; ++wi) {
        int wrow = (2 * q + wi) * 16 + r;
#pragma unroll
        for (int ks = 0; ks < 4; ++ks) {
            int slot = (ks * 4 + g) ^ (wrow & 7);
            a[wi][ks] = *(const f16x8*)&s_src[wrow * 128 + slot * 8];
        }
    }

    float* outb = out + (size_t)b * (NKD * NKD) * (HH * WW) + (size_t)h * WW;

    // vmcnt FIFO per wave (3 loads/stage, 24 stores/epilogue, in-order retire):
    //  cc0: [t, t+1, t+2, S]  -> vmcnt(30) retires t
    //  cc1: [t, t+1, S, t+2]  -> vmcnt(30)
    //  cc2: [t, S, t+1, t+2]  -> vmcnt(30)
    //  cc3: [S, t, t+1, t+2]  -> vmcnt(6) retires S and t
    //  dy=20 tail: cc2 -> vmcnt(27), cc3 -> vmcnt(0)
    // stage(t+3) is issued AFTER the barrier -> slot (t-1)&3 overwrite is race-free
    // (all waves finished phase t-1 reads at barrier t).
#define PHASE_COMPUTE(cc_, t_)                                                        \
    {                                                                                 \
        const char* buf = s_ring + (size_t)((t_) & 3) * CH_BYTES;                     \
        f16x8 bfr[4];                                                                 \
        _Pragma("unroll")                                                             \
        for (int pi = 0; pi < 4; ++pi)                                                \
            bfr[pi] = *(const f16x8*)(buf + ((2 * q + pi) * 16 + r) * 80 + g * 16);   \
        _Pragma("unroll")                                                             \
        for (int wi = 0; wi < 2; ++wi)                                                \
            _Pragma("unroll")                                                         \
            for (int pj = 0; pj < 3; ++pj)                                            \
                acc[wi][pj] = __builtin_amdgcn_mfma_f32_16x16x32_f16(                 \
                    bfr[wi + pj], a[wi][cc_], acc[wi][pj], 0, 0, 0);                  \
    }

#define EPILOGUE(dy_)                                                                 \
    _Pragma("unroll")                                                                 \
    for (int wi = 0; wi < 2; ++wi) {                                                  \
        int w = (2 * q + wi) * 16 + r;                                                \
        float* op = outb + (size_t)(dy_) * NKD * (HH * WW) + w;                       \
        _Pragma("unroll")                                                             \
        for (int pj = 0; pj < 3; ++pj)                                                \
            _Pragma("unroll")                                                         \
            for (int j = 0; j < 4; ++j) {                                             \
                int dxv = pj * 16 + 4 * g + j - r;                                    \
                if (dxv >= 0 && dxv < NKD)                                            \
                    op[(size_t)dxv * (HH * WW)] = acc[wi][pj][j];                     \
            }                                                                         \
    }

    for (int dy = 0; dy < NKD - 1; ++dy) {
        f32x4 acc[2][3];
#pragma unroll
        for (int wi = 0; wi < 2; ++wi)
#pragma unroll
            for (int pj = 0; pj < 3; ++pj)
#pragma unroll
                for (int j = 0; j < 4; ++j) acc[wi][pj][j] = 0.f;

#pragma unroll
        for (int cc = 0; cc < 4; ++cc) {
            int t = dy * 4 + cc;
            if (cc < 3) asm volatile("s_waitcnt vmcnt(30)" ::: "memory");
            else        asm volatile("s_waitcnt vmcnt(6)"  ::: "memory");
            __builtin_amdgcn_s_barrier();
            __builtin_amdgcn_sched_barrier(0);
            stage(t + 3);
            PHASE_COMPUTE(cc, t)
        }
        EPILOGUE(dy)
    }

    {   // dy = 20 tail (no further stages except chunk 83 at cc0)
        const int dy = NKD - 1;
        f32x4 acc[2][3];
#pragma unroll
        for (int wi = 0; wi < 2; ++wi)
#pragma unroll
            for (int pj = 0; pj < 3; ++pj)
#pragma unroll
                for (int j = 0; j < 4; ++j) acc[wi][pj][j] = 0.f;

#pragma unroll
        for (int cc = 0; cc < 4; ++cc) {
            int t = dy * 4 + cc;
            if (cc < 2)       asm volatile("s_waitcnt vmcnt(30)" ::: "memory");
            else if (cc == 2) asm volatile("s_waitcnt vmcnt(27)" ::: "memory");
            else              asm volatile("s_waitcnt vmcnt(0)"  ::: "memory");
            __builtin_amdgcn_s_barrier();
            __builtin_amdgcn_sched_barrier(0);
            if (cc == 0) stage(t + 3);
            PHASE_COMPUTE(cc, t)
        }
        EPILOGUE(dy)
    }
}

extern "C" void kernel_launch(void* const* d_in, const int* in_sizes, int n_in,
                              void* d_out, int out_size, void* d_ws, size_t ws_size,
                              hipStream_t stream) {
    const float* in = (const float*)d_in[0];
    float* out = (float*)d_out;
    __fp16* img_tgt = (__fp16*)d_ws;

    hipLaunchKernelGGL(pack_tgt, dim3(4 * HPAD), dim3(256), 0, stream, in, img_tgt);
    hipLaunchKernelGGL(corr_mfma, dim3(512), dim3(256), 0, stream, in, img_tgt, out);
}

// Round 10
// 61.504 us; speedup vs baseline: 1.4471x; 1.4471x over previous
//
#include <hip/hip_runtime.h>

#define HH 128
#define WW 128
#define CCH 128
#define NKD 21
#define RAD 10
#define HPAD 148                 // tgt images per b (hp = h+dy, 0..147)
#define ROWH 40                  // halves per row (32c + 8 pad) = 80B
#define CH_HALVES (148 * ROWH)   // 5920 halves per chunk (148 p-rows)
#define CH_BYTES  (CH_HALVES * 2)        // 11840 B
#define IMG_HALVES (4 * CH_HALVES)       // 23680 halves per (b,hp) = 47360 B

typedef _Float16 f16x8 __attribute__((ext_vector_type(8)));
typedef float    f32x4 __attribute__((ext_vector_type(4)));
typedef __fp16   h2f   __attribute__((ext_vector_type(2)));

union PK { uint4 u; h2f h[4]; };

// ------- kernel 1: pack tgt -> f16 image [hp][chunk(32c)][p(148)][40 halves], zero-padded -------
__global__ __launch_bounds__(256)
void pack_tgt(const float* __restrict__ in, __fp16* __restrict__ img) {
    int n = blockIdx.x;                 // 592: b*148 + i (tgt row = i-10)
    int b = n / HPAD, i = n - b * HPAD;
    int tid = threadIdx.x;
    uint4* gi = (uint4*)(img + (size_t)n * IMG_HALVES);
    if (i < RAD || i > 137) {           // h out of range -> all-zero image (2960 uint4)
        uint4 z = make_uint4(0, 0, 0, 0);
#pragma unroll
        for (int k = 0; k < 11; ++k) gi[k * 256 + tid] = z;
        if (tid < 144) gi[11 * 256 + tid] = z;
        return;
    }
    __shared__ __align__(16) char sraw[4 * CH_BYTES];   // 46.25KB
    {   // zero-fill (covers p<10, p>137 pad rows and the 8-half row tail)
        uint4 z = make_uint4(0, 0, 0, 0);
        uint4* sp = (uint4*)sraw;
#pragma unroll
        for (int k = 0; k < 11; ++k) sp[k * 256 + tid] = z;
        if (tid < 144) sp[11 * 256 + tid] = z;
    }
    __syncthreads();
    const float* tg = in + (size_t)(b * 2 + 1) * CCH * HH * WW + (size_t)(i - RAD) * WW;
    int w = tid & 127, half = tid >> 7;
    int p = w + RAD;                    // 10..137
#pragma unroll
    for (int c2 = 0; c2 < 2; ++c2) {
        int cc = half * 2 + c2;         // chunk 0..3 (32 channels each)
#pragma unroll
        for (int g = 0; g < 4; ++g) {   // slot g = halves c_local g*8..g*8+7
            float v[8];
#pragma unroll
            for (int j = 0; j < 8; ++j)
                v[j] = tg[(size_t)(cc * 32 + g * 8 + j) * (HH * WW) + w];
            PK q;
            q.h[0] = __builtin_amdgcn_cvt_pkrtz(v[0], v[1]);
            q.h[1] = __builtin_amdgcn_cvt_pkrtz(v[2], v[3]);
            q.h[2] = __builtin_amdgcn_cvt_pkrtz(v[4], v[5]);
            q.h[3] = __builtin_amdgcn_cvt_pkrtz(v[6], v[7]);
            *(uint4*)(sraw + (size_t)cc * CH_BYTES + p * 80 + g * 16) = q.u;
        }
    }
    __syncthreads();
    const uint4* si = (const uint4*)sraw;
#pragma unroll
    for (int k = 0; k < 11; ++k) gi[k * 256 + tid] = si[k * 256 + tid];
    if (tid < 144) gi[11 * 256 + tid] = si[11 * 256 + tid];
}

// -------- kernel 2: 2-row block; each wave computes both rows from one staged chunk --------
// image hp = h0+ph serves row0 (dy=ph) and row1 (dy=ph-1): DMA and bfr reads halved/output.
// MFMA operand order: a (w-rows) FIRST, bfr (p-cols) SECOND -> acc rows=w(4g+j), cols=p(r).
// OOB band reads (prow>=148) contaminate only acc cols that the epilogue never reads.
__global__ __launch_bounds__(256, 1)
void corr_mfma(const float* __restrict__ in, const __fp16* __restrict__ img_tgt,
               float* __restrict__ out) {
    int n = blockIdx.x;                 // 256
    int xcd = n & 7, idx = n >> 3;
    int gl = xcd * 32 + idx;            // h-pair-contiguous per XCD
    int b = gl >> 6;                    // 0..3
    int h0 = (gl & 63) << 1;            // even row base

    // [ring 4 x 11840B][overlay 32KB: s_src then s_o] = 80128B
    __shared__ __align__(16) char smem[4 * CH_BYTES + 32768];
    char*   s_ring = smem;
    __fp16* s_src  = (__fp16*)(smem + 4 * CH_BYTES);
    float*  s_o    = (float*)(smem + 4 * CH_BYTES);

    int tid = threadIdx.x;
    int q = tid >> 6, lane = tid & 63, r = lane & 15, g = lane >> 4;

    const __fp16* tgb = img_tgt + (size_t)(b * HPAD) * IMG_HALVES;

    // DMA chunk t = ph*4+cc (image h0+ph) into ring slot t&3; wave q copies 185 uint4
    auto stage = [&](int t) {
        int ph = t >> 2, cc = t & 3;
        const uint4* gp = (const uint4*)(tgb + ((size_t)(h0 + ph) * 4 + cc) * CH_HALVES)
                          + q * 185 + lane;
        char* lb = s_ring + (size_t)(t & 3) * CH_BYTES + q * 2960;
        __builtin_amdgcn_global_load_lds(
            (const __attribute__((address_space(1))) void*)gp,
            (__attribute__((address_space(3))) void*)lb, 16, 0, 0);
        __builtin_amdgcn_global_load_lds(
            (const __attribute__((address_space(1))) void*)(gp + 64),
            (__attribute__((address_space(3))) void*)(lb + 1024), 16, 0, 0);
        if (lane < 57)
            __builtin_amdgcn_global_load_lds(
                (const __attribute__((address_space(1))) void*)(gp + 128),
                (__attribute__((address_space(3))) void*)(lb + 2048), 16, 0, 0);
    };

    stage(0);
    stage(1);

    // ---- pack both src rows through the 32KB overlay; A-frags to regs ----
    f16x8 a[2][2][4];   // [row][wi][cc-group]
#pragma unroll
    for (int row = 0; row < 2; ++row) {
        const float* src = in + (size_t)(b * 2) * CCH * HH * WW + (size_t)(h0 + row) * WW;
        const float sc = 1.f / 128.f;
        int w = tid & 127, half = tid >> 7;
#pragma unroll
        for (int t8 = 0; t8 < 8; ++t8) {
            int t = half * 8 + t8;          // c-block 0..15
            float v[8];
#pragma unroll
            for (int j = 0; j < 8; ++j) v[j] = src[(size_t)(t * 8 + j) * (HH * WW) + w] * sc;
            PK qq;
            qq.h[0] = __builtin_amdgcn_cvt_pkrtz(v[0], v[1]);
            qq.h[1] = __builtin_amdgcn_cvt_pkrtz(v[2], v[3]);
            qq.h[2] = __builtin_amdgcn_cvt_pkrtz(v[4], v[5]);
            qq.h[3] = __builtin_amdgcn_cvt_pkrtz(v[6], v[7]);
            int slot = t ^ (w & 7);
            *(uint4*)&s_src[w * 128 + slot * 8] = qq.u;
        }
        __syncthreads();
#pragma unroll
        for (int wi = 0; wi < 2; ++wi) {
            int wrow = (2 * q + wi) * 16 + r;
#pragma unroll
            for (int ks = 0; ks < 4; ++ks) {
                int slot = (ks * 4 + g) ^ (wrow & 7);
                a[row][wi][ks] = *(const f16x8*)&s_src[wrow * 128 + slot * 8];
            }
        }
        asm volatile("s_waitcnt lgkmcnt(0)" ::: "memory");
        __syncthreads();   // frags in regs everywhere before re-pack / s_o overlay
    }

    float* outb = out + (size_t)b * (NKD * NKD) * (HH * WW) + (size_t)h0 * WW;
    float* so = s_o + q * (32 * 50);

    // vmcnt FIFO per wave: 3 loads/stage, 3 stores per epilogue-row (up to 6/ph).
    // cc0/cc1 -> vmcnt(6); cc2/cc3 -> vmcnt(3); t=87 -> vmcnt(0). Hand-traced at
    // ph=0 (post-sync drain), ph=1 (3 stores), steady (6 stores), ph=21 tail.
    // Stage AFTER barrier: slot t-2 overwrite has >=2-barrier margin -> race-free.
    for (int ph = 0; ph < 22; ++ph) {
        f32x4 acc[2][2][3];   // [row][wi][pj]
#pragma unroll
        for (int row = 0; row < 2; ++row)
#pragma unroll
            for (int wi = 0; wi < 2; ++wi)
#pragma unroll
                for (int pj = 0; pj < 3; ++pj)
#pragma unroll
                    for (int j = 0; j < 4; ++j) acc[row][wi][pj][j] = 0.f;

#pragma unroll
        for (int cc = 0; cc < 4; ++cc) {
            int t = ph * 4 + cc;
            if (cc < 2)       asm volatile("s_waitcnt vmcnt(6)" ::: "memory");
            else if (t == 87) asm volatile("s_waitcnt vmcnt(0)" ::: "memory");
            else              asm volatile("s_waitcnt vmcnt(3)" ::: "memory");
            __builtin_amdgcn_s_barrier();
            __builtin_amdgcn_sched_barrier(0);
            if (t + 2 < 88) stage(t + 2);

            const char* buf = s_ring + (size_t)(t & 3) * CH_BYTES;
            f16x8 bfr[4];
#pragma unroll
            for (int pi = 0; pi < 4; ++pi)
                bfr[pi] = *(const f16x8*)(buf + ((2 * q + pi) * 16 + r) * 80 + g * 16);

            if (ph < 21) {
#pragma unroll
                for (int wi = 0; wi < 2; ++wi)
#pragma unroll
                    for (int pj = 0; pj < 3; ++pj)
                        acc[0][wi][pj] = __builtin_amdgcn_mfma_f32_16x16x32_f16(
                            a[0][wi][cc], bfr[wi + pj], acc[0][wi][pj], 0, 0, 0);
            }
            if (ph > 0) {
#pragma unroll
                for (int wi = 0; wi < 2; ++wi)
#pragma unroll
                    for (int pj = 0; pj < 3; ++pj)
                        acc[1][wi][pj] = __builtin_amdgcn_mfma_f32_16x16x32_f16(
                            a[1][wi][cc], bfr[wi + pj], acc[1][wi][pj], 0, 0, 0);
            }
        }

        // ---- staggered epilogues: row0 dy=ph, row1 dy=ph-1 (s_o slab reused serially) ----
#pragma unroll
        for (int row = 0; row < 2; ++row) {
            int dy = ph - row;
            if (dy < 0 || dy >= NKD) continue;
#pragma unroll
            for (int wi = 0; wi < 2; ++wi)
#pragma unroll
                for (int pj = 0; pj < 3; ++pj)
#pragma unroll
                    for (int j = 0; j < 4; ++j)
                        so[(wi * 16 + 4 * g + j) * 50 + pj * 16 + r] = acc[row][wi][pj][j];
            asm volatile("s_waitcnt lgkmcnt(0)" ::: "memory");
            __builtin_amdgcn_sched_barrier(0);
            float* op = outb + (size_t)row * WW + (size_t)dy * NKD * (HH * WW);
#pragma unroll
            for (int k = 0; k < 3; ++k) {     // exactly 3 store instrs per wave
                int f = k * 64 + lane;
                if (f < NKD * 8) {
                    int dx = f >> 3, w4l = (f & 7) << 2;   // local w in wave's 32-w slab
                    float4 v;
                    v.x = so[(w4l + 0) * 50 + ((w4l + 0) & 15) + dx];
                    v.y = so[(w4l + 1) * 50 + ((w4l + 1) & 15) + dx];
                    v.z = so[(w4l + 2) * 50 + ((w4l + 2) & 15) + dx];
                    v.w = so[(w4l + 3) * 50 + ((w4l + 3) & 15) + dx];
                    *(float4*)&op[(size_t)dx * (HH * WW) + q * 32 + w4l] = v;
                }
            }
            asm volatile("s_waitcnt lgkmcnt(0)" ::: "memory");  // reads done before row1 rewrites
        }
    }
}

extern "C" void kernel_launch(void* const* d_in, const int* in_sizes, int n_in,
                              void* d_out, int out_size, void* d_ws, size_t ws_size,
                              hipStream_t stream) {
    const float* in = (const float*)d_in[0];
    float* out = (float*)d_out;
    __fp16* img_tgt = (__fp16*)d_ws;

    hipLaunchKernelGGL(pack_tgt, dim3(4 * HPAD), dim3(256), 0, stream, in, img_tgt);
    hipLaunchKernelGGL(corr_mfma, dim3(256), dim3(256), 0, stream, in, img_tgt, out);
}

// Round 11
// 60.072 us; speedup vs baseline: 1.4815x; 1.0238x over previous
//
#include <hip/hip_runtime.h>

#define HH 128
#define WW 128
#define CCH 128
#define NKD 21
#define RAD 10
#define HPAD 148                 // tgt images per b (hp = h+dy, 0..147)
#define ROWH 40                  // halves per row (32c + 8 pad) = 80B
#define CH_HALVES (148 * ROWH)   // 5920 halves per chunk (148 p-rows)
#define CH_BYTES  (CH_HALVES * 2)        // 11840 B
#define IMG_HALVES (4 * CH_HALVES)       // 23680 halves per (b,hp) = 47360 B

typedef _Float16 f16x8 __attribute__((ext_vector_type(8)));
typedef float    f32x4 __attribute__((ext_vector_type(4)));
typedef __fp16   h2f   __attribute__((ext_vector_type(2)));

union PK { uint4 u; h2f h[4]; };

// ------- kernel 1: pack tgt -> f16 image [hp][chunk(32c)][p(148)][40 halves], zero-padded -------
__global__ __launch_bounds__(256)
void pack_tgt(const float* __restrict__ in, __fp16* __restrict__ img) {
    int n = blockIdx.x;                 // 592: b*148 + i (tgt row = i-10)
    int b = n / HPAD, i = n - b * HPAD;
    int tid = threadIdx.x;
    uint4* gi = (uint4*)(img + (size_t)n * IMG_HALVES);
    if (i < RAD || i > 137) {           // h out of range -> all-zero image (2960 uint4)
        uint4 z = make_uint4(0, 0, 0, 0);
#pragma unroll
        for (int k = 0; k < 11; ++k) gi[k * 256 + tid] = z;
        if (tid < 144) gi[11 * 256 + tid] = z;
        return;
    }
    __shared__ __align__(16) char sraw[4 * CH_BYTES];   // 46.25KB
    {   // zero-fill (covers p<10, p>137 pad rows and the 8-half row tail)
        uint4 z = make_uint4(0, 0, 0, 0);
        uint4* sp = (uint4*)sraw;
#pragma unroll
        for (int k = 0; k < 11; ++k) sp[k * 256 + tid] = z;
        if (tid < 144) sp[11 * 256 + tid] = z;
    }
    __syncthreads();
    const float* tg = in + (size_t)(b * 2 + 1) * CCH * HH * WW + (size_t)(i - RAD) * WW;
    int w = tid & 127, half = tid >> 7;
    int p = w + RAD;                    // 10..137
#pragma unroll
    for (int c2 = 0; c2 < 2; ++c2) {
        int cc = half * 2 + c2;         // chunk 0..3 (32 channels each)
#pragma unroll
        for (int g = 0; g < 4; ++g) {   // slot g = halves c_local g*8..g*8+7
            float v[8];
#pragma unroll
            for (int j = 0; j < 8; ++j)
                v[j] = tg[(size_t)(cc * 32 + g * 8 + j) * (HH * WW) + w];
            PK q;
            q.h[0] = __builtin_amdgcn_cvt_pkrtz(v[0], v[1]);
            q.h[1] = __builtin_amdgcn_cvt_pkrtz(v[2], v[3]);
            q.h[2] = __builtin_amdgcn_cvt_pkrtz(v[4], v[5]);
            q.h[3] = __builtin_amdgcn_cvt_pkrtz(v[6], v[7]);
            *(uint4*)(sraw + (size_t)cc * CH_BYTES + p * 80 + g * 16) = q.u;
        }
    }
    __syncthreads();
    const uint4* si = (const uint4*)sraw;
#pragma unroll
    for (int k = 0; k < 11; ++k) gi[k * 256 + tid] = si[k * 256 + tid];
    if (tid < 144) gi[11 * 256 + tid] = si[11 * 256 + tid];
}

// -------- kernel 2: 2-row block; each wave computes both rows from one staged chunk --------
// image hp = h0+ph serves row0 (dy=ph) and row1 (dy=ph-1): DMA and bfr reads halved/output.
// MFMA operand order: a (w-rows) FIRST, bfr (p-cols) SECOND -> acc rows=w(4g+j), cols=p(r).
__global__ __launch_bounds__(256, 2)
void corr_mfma(const float* __restrict__ in, const __fp16* __restrict__ img_tgt,
               float* __restrict__ out) {
    int n = blockIdx.x;                 // 256
    int xcd = n & 7, idx = n >> 3;
    int gl = xcd * 32 + idx;            // h-pair-contiguous per XCD
    int b = gl >> 6;                    // 0..3
    int h0 = (gl & 63) << 1;            // even row base

    // [ring 4 x 11840B][overlay 25.6KB: s_srch(16KB) then s_o] = 72960B -> 2 blocks/CU
    __shared__ __align__(16) char smem[4 * CH_BYTES + 25600];
    char*   s_ring = smem;
    __fp16* s_srch = (__fp16*)(smem + 4 * CH_BYTES);   // 128w x 64c half-buffer
    float*  s_o    = (float*)(smem + 4 * CH_BYTES);

    int tid = threadIdx.x;
    int q = tid >> 6, lane = tid & 63, r = lane & 15, g = lane >> 4;

    const __fp16* tgb = img_tgt + (size_t)(b * HPAD) * IMG_HALVES;

    // DMA chunk t = ph*4+cc (image h0+ph) into ring slot t&3; wave q copies 185 uint4
    auto stage = [&](int t) {
        int ph = t >> 2, cc = t & 3;
        const uint4* gp = (const uint4*)(tgb + ((size_t)(h0 + ph) * 4 + cc) * CH_HALVES)
                          + q * 185 + lane;
        char* lb = s_ring + (size_t)(t & 3) * CH_BYTES + q * 2960;
        __builtin_amdgcn_global_load_lds(
            (const __attribute__((address_space(1))) void*)gp,
            (__attribute__((address_space(3))) void*)lb, 16, 0, 0);
        __builtin_amdgcn_global_load_lds(
            (const __attribute__((address_space(1))) void*)(gp + 64),
            (__attribute__((address_space(3))) void*)(lb + 1024), 16, 0, 0);
        if (lane < 57)
            __builtin_amdgcn_global_load_lds(
                (const __attribute__((address_space(1))) void*)(gp + 128),
                (__attribute__((address_space(3))) void*)(lb + 2048), 16, 0, 0);
    };

    stage(0);
    stage(1);

    // ---- pack src rows via 16KB c-half buffer; A-frags to regs ----
    f16x8 a[2][2][4];   // [row][wi][cc-group]
#pragma unroll
    for (int row = 0; row < 2; ++row) {
        const float* src = in + (size_t)(b * 2) * CCH * HH * WW + (size_t)(h0 + row) * WW;
        const float sc = 1.f / 128.f;
        int w = tid & 127, hb = tid >> 7;
#pragma unroll
        for (int chalf = 0; chalf < 2; ++chalf) {
#pragma unroll
            for (int i4 = 0; i4 < 4; ++i4) {
                int t4 = hb * 4 + i4;           // c-block within half, 0..7
                float v[8];
#pragma unroll
                for (int j = 0; j < 8; ++j)
                    v[j] = src[(size_t)(chalf * 64 + t4 * 8 + j) * (HH * WW) + w] * sc;
                PK qq;
                qq.h[0] = __builtin_amdgcn_cvt_pkrtz(v[0], v[1]);
                qq.h[1] = __builtin_amdgcn_cvt_pkrtz(v[2], v[3]);
                qq.h[2] = __builtin_amdgcn_cvt_pkrtz(v[4], v[5]);
                qq.h[3] = __builtin_amdgcn_cvt_pkrtz(v[6], v[7]);
                int slot = t4 ^ (w & 7);
                *(uint4*)&s_srch[w * 64 + slot * 8] = qq.u;
            }
            __syncthreads();
#pragma unroll
            for (int wi = 0; wi < 2; ++wi) {
                int wrow = (2 * q + wi) * 16 + r;
#pragma unroll
                for (int ksl = 0; ksl < 2; ++ksl) {
                    int slot = (ksl * 4 + g) ^ (wrow & 7);
                    a[row][wi][chalf * 2 + ksl] = *(const f16x8*)&s_srch[wrow * 64 + slot * 8];
                }
            }
            asm volatile("s_waitcnt lgkmcnt(0)" ::: "memory");
            __syncthreads();   // frags in regs everywhere before re-pack / s_o overlay
        }
    }

    float* outb = out + (size_t)b * (NKD * NKD) * (HH * WW) + (size_t)h0 * WW;
    float* so = s_o + q * (32 * 50);

    // vmcnt FIFO per wave: 3 loads/stage, 3 stores/epilogue-row (SEPI: ph0=3, 1..20=6, 21=3).
    // Entering cc0(t): FIFO [L(t)3, L(t+1)3, SEPI(ph-1)] -> allow L(t+1)+S behind:
    //   ph<=1 -> vmcnt(6), else vmcnt(9).
    // cc1: [L(t+1)3, S, L(t+2)3] -> same counts. cc2: [S.., L(t+2)3, L(t+3)3], S older
    //   -> vmcnt(3). cc3: [L(t+3)3, L(t+4)3] -> vmcnt(3); t=87 -> vmcnt(0).
    // Stage AFTER barrier: slot t-2 overwrite has >=2-barrier margin -> race-free.
    for (int ph = 0; ph < 22; ++ph) {
        f32x4 acc[2][2][3];   // [row][wi][pj]
#pragma unroll
        for (int row = 0; row < 2; ++row)
#pragma unroll
            for (int wi = 0; wi < 2; ++wi)
#pragma unroll
                for (int pj = 0; pj < 3; ++pj)
#pragma unroll
                    for (int j = 0; j < 4; ++j) acc[row][wi][pj][j] = 0.f;

#pragma unroll
        for (int cc = 0; cc < 4; ++cc) {
            int t = ph * 4 + cc;
            if (cc < 2) {
                if (ph <= 1) asm volatile("s_waitcnt vmcnt(6)" ::: "memory");
                else         asm volatile("s_waitcnt vmcnt(9)" ::: "memory");
            } else if (t == 87) {
                asm volatile("s_waitcnt vmcnt(0)" ::: "memory");
            } else {
                asm volatile("s_waitcnt vmcnt(3)" ::: "memory");
            }
            __builtin_amdgcn_s_barrier();
            __builtin_amdgcn_sched_barrier(0);
            if (t + 2 < 88) stage(t + 2);

            const char* buf = s_ring + (size_t)(t & 3) * CH_BYTES;
            f16x8 bfr[4];
#pragma unroll
            for (int pi = 0; pi < 4; ++pi)
                bfr[pi] = *(const f16x8*)(buf + ((2 * q + pi) * 16 + r) * 80 + g * 16);

            if (ph < 21) {
#pragma unroll
                for (int wi = 0; wi < 2; ++wi)
#pragma unroll
                    for (int pj = 0; pj < 3; ++pj)
                        acc[0][wi][pj] = __builtin_amdgcn_mfma_f32_16x16x32_f16(
                            a[0][wi][cc], bfr[wi + pj], acc[0][wi][pj], 0, 0, 0);
            }
            if (ph > 0) {
#pragma unroll
                for (int wi = 0; wi < 2; ++wi)
#pragma unroll
                    for (int pj = 0; pj < 3; ++pj)
                        acc[1][wi][pj] = __builtin_amdgcn_mfma_f32_16x16x32_f16(
                            a[1][wi][cc], bfr[wi + pj], acc[1][wi][pj], 0, 0, 0);
            }
        }

        // ---- staggered epilogues: row0 dy=ph, row1 dy=ph-1 (s_o slab wave-private) ----
#pragma unroll
        for (int row = 0; row < 2; ++row) {
            int dy = ph - row;
            if (dy < 0 || dy >= NKD) continue;
#pragma unroll
            for (int wi = 0; wi < 2; ++wi)
#pragma unroll
                for (int pj = 0; pj < 3; ++pj)
#pragma unroll
                    for (int j = 0; j < 4; ++j)
                        so[(wi * 16 + 4 * g + j) * 50 + pj * 16 + r] = acc[row][wi][pj][j];
            asm volatile("s_waitcnt lgkmcnt(0)" ::: "memory");
            __builtin_amdgcn_sched_barrier(0);
            float* op = outb + (size_t)row * WW + (size_t)dy * NKD * (HH * WW);
#pragma unroll
            for (int k = 0; k < 3; ++k) {     // exactly 3 store instrs per wave
                int f = k * 64 + lane;
                if (f < NKD * 8) {
                    int dx = f >> 3, w4l = (f & 7) << 2;   // local w in wave's 32-w slab
                    float4 v;
                    v.x = so[(w4l + 0) * 50 + ((w4l + 0) & 15) + dx];
                    v.y = so[(w4l + 1) * 50 + ((w4l + 1) & 15) + dx];
                    v.z = so[(w4l + 2) * 50 + ((w4l + 2) & 15) + dx];
                    v.w = so[(w4l + 3) * 50 + ((w4l + 3) & 15) + dx];
                    *(float4*)&op[(size_t)dx * (HH * WW) + q * 32 + w4l] = v;
                }
            }
            asm volatile("s_waitcnt lgkmcnt(0)" ::: "memory");  // reads done before row1 rewrites
        }
    }
}

extern "C" void kernel_launch(void* const* d_in, const int* in_sizes, int n_in,
                              void* d_out, int out_size, void* d_ws, size_t ws_size,
                              hipStream_t stream) {
    const float* in = (const float*)d_in[0];
    float* out = (float*)d_out;
    __fp16* img_tgt = (__fp16*)d_ws;

    hipLaunchKernelGGL(pack_tgt, dim3(4 * HPAD), dim3(256), 0, stream, in, img_tgt);
    hipLaunchKernelGGL(corr_mfma, dim3(256), dim3(256), 0, stream, in, img_tgt, out);
}

// Round 12
// 57.131 us; speedup vs baseline: 1.5578x; 1.0515x over previous
//
#include <hip/hip_runtime.h>

#define HH 128
#define WW 128
#define CCH 128
#define NKD 21
#define RAD 10
#define HPAD 148                 // tgt images per b (hp = h+dy, 0..147)
#define ROWH 40                  // halves per row (32c + 8 pad) = 80B
#define CH_HALVES (148 * ROWH)   // 5920 halves per chunk (148 p-rows)
#define CH_BYTES  (CH_HALVES * 2)        // 11840 B
#define IMG_HALVES (4 * CH_HALVES)       // 23680 halves per (b,hp) = 47360 B

typedef _Float16 f16x8 __attribute__((ext_vector_type(8)));
typedef float    f32x4 __attribute__((ext_vector_type(4)));
typedef __fp16   h2f   __attribute__((ext_vector_type(2)));

union PK { uint4 u; h2f h[4]; };

// ------- kernel 1: pack tgt -> f16 image [hp][chunk(32c)][p(148)][40 halves], zero-padded -------
__global__ __launch_bounds__(256)
void pack_tgt(const float* __restrict__ in, __fp16* __restrict__ img) {
    int n = blockIdx.x;                 // 592: b*148 + i (tgt row = i-10)
    int b = n / HPAD, i = n - b * HPAD;
    int tid = threadIdx.x;
    uint4* gi = (uint4*)(img + (size_t)n * IMG_HALVES);
    if (i < RAD || i > 137) {           // h out of range -> all-zero image (2960 uint4)
        uint4 z = make_uint4(0, 0, 0, 0);
#pragma unroll
        for (int k = 0; k < 11; ++k) gi[k * 256 + tid] = z;
        if (tid < 144) gi[11 * 256 + tid] = z;
        return;
    }
    __shared__ __align__(16) char sraw[4 * CH_BYTES];   // 46.25KB
    {   // zero-fill (covers p<10, p>137 pad rows and the 8-half row tail)
        uint4 z = make_uint4(0, 0, 0, 0);
        uint4* sp = (uint4*)sraw;
#pragma unroll
        for (int k = 0; k < 11; ++k) sp[k * 256 + tid] = z;
        if (tid < 144) sp[11 * 256 + tid] = z;
    }
    __syncthreads();
    const float* tg = in + (size_t)(b * 2 + 1) * CCH * HH * WW + (size_t)(i - RAD) * WW;
    int w = tid & 127, half = tid >> 7;
    int p = w + RAD;                    // 10..137
#pragma unroll
    for (int c2 = 0; c2 < 2; ++c2) {
        int cc = half * 2 + c2;         // chunk 0..3 (32 channels each)
#pragma unroll
        for (int g = 0; g < 4; ++g) {   // slot g = halves c_local g*8..g*8+7
            float v[8];
#pragma unroll
            for (int j = 0; j < 8; ++j)
                v[j] = tg[(size_t)(cc * 32 + g * 8 + j) * (HH * WW) + w];
            PK q;
            q.h[0] = __builtin_amdgcn_cvt_pkrtz(v[0], v[1]);
            q.h[1] = __builtin_amdgcn_cvt_pkrtz(v[2], v[3]);
            q.h[2] = __builtin_amdgcn_cvt_pkrtz(v[4], v[5]);
            q.h[3] = __builtin_amdgcn_cvt_pkrtz(v[6], v[7]);
            *(uint4*)(sraw + (size_t)cc * CH_BYTES + p * 80 + g * 16) = q.u;
        }
    }
    __syncthreads();
    const uint4* si = (const uint4*)sraw;
#pragma unroll
    for (int k = 0; k < 11; ++k) gi[k * 256 + tid] = si[k * 256 + tid];
    if (tid < 144) gi[11 * 256 + tid] = si[11 * 256 + tid];
}

// -------- kernel 2: 2-row block, dy-SPLIT across 2 blocks (grid 512 -> 2 blocks/CU) --------
// Block d covers hp = h0 + d*11 + phl, phl=0..10. row0 dy = ph_g (skip if >20),
// row1 dy = ph_g-1 (skip if <0). Partition: row0 0..10|11..20, row1 0..9|10..20.
// MFMA operand order: a (w-rows) FIRST, bfr (p-cols) SECOND -> acc rows=w(4g+j), cols=p(r).
__global__ __launch_bounds__(256, 2)
void corr_mfma(const float* __restrict__ in, const __fp16* __restrict__ img_tgt,
               float* __restrict__ out) {
    int n = blockIdx.x;                 // 512
    int xcd = n & 7, idx = n >> 3;
    int u = xcd * 64 + idx;             // A/B pairs adjacent on one XCD
    int d = u & 1;                      // dy-split half
    int hpair = u >> 1;                 // 0..255
    int b = hpair >> 6;                 // 0..3
    int h0 = (hpair & 63) << 1;         // even row base

    // [ring 4 x 11840B][overlay 25.6KB: s_srch(16KB) then s_o] = 72960B -> 2 blocks/CU
    __shared__ __align__(16) char smem[4 * CH_BYTES + 25600];
    char*   s_ring = smem;
    __fp16* s_srch = (__fp16*)(smem + 4 * CH_BYTES);   // 128w x 64c half-buffer
    float*  s_o    = (float*)(smem + 4 * CH_BYTES);

    int tid = threadIdx.x;
    int q = tid >> 6, lane = tid & 63, r = lane & 15, g = lane >> 4;

    const __fp16* tgb = img_tgt + (size_t)(b * HPAD) * IMG_HALVES;
    const int hbase = h0 + d * 11;      // hp = hbase + (t>>2), max 126+11+10 = 147 ok

    // DMA local chunk t (0..43) into ring slot t&3; wave q copies 185 uint4
    auto stage = [&](int t) {
        const uint4* gp = (const uint4*)(tgb + ((size_t)(hbase + (t >> 2)) * 4 + (t & 3)) * CH_HALVES)
                          + q * 185 + lane;
        char* lb = s_ring + (size_t)(t & 3) * CH_BYTES + q * 2960;
        __builtin_amdgcn_global_load_lds(
            (const __attribute__((address_space(1))) void*)gp,
            (__attribute__((address_space(3))) void*)lb, 16, 0, 0);
        __builtin_amdgcn_global_load_lds(
            (const __attribute__((address_space(1))) void*)(gp + 64),
            (__attribute__((address_space(3))) void*)(lb + 1024), 16, 0, 0);
        if (lane < 57)
            __builtin_amdgcn_global_load_lds(
                (const __attribute__((address_space(1))) void*)(gp + 128),
                (__attribute__((address_space(3))) void*)(lb + 2048), 16, 0, 0);
    };

    stage(0);
    stage(1);

    // ---- pack src rows via 16KB c-half buffer; A-frags to regs ----
    f16x8 a[2][2][4];   // [row][wi][cc-group]
#pragma unroll
    for (int row = 0; row < 2; ++row) {
        const float* src = in + (size_t)(b * 2) * CCH * HH * WW + (size_t)(h0 + row) * WW;
        const float sc = 1.f / 128.f;
        int w = tid & 127, hb = tid >> 7;
#pragma unroll
        for (int chalf = 0; chalf < 2; ++chalf) {
#pragma unroll
            for (int i4 = 0; i4 < 4; ++i4) {
                int t4 = hb * 4 + i4;           // c-block within half, 0..7
                float v[8];
#pragma unroll
                for (int j = 0; j < 8; ++j)
                    v[j] = src[(size_t)(chalf * 64 + t4 * 8 + j) * (HH * WW) + w] * sc;
                PK qq;
                qq.h[0] = __builtin_amdgcn_cvt_pkrtz(v[0], v[1]);
                qq.h[1] = __builtin_amdgcn_cvt_pkrtz(v[2], v[3]);
                qq.h[2] = __builtin_amdgcn_cvt_pkrtz(v[4], v[5]);
                qq.h[3] = __builtin_amdgcn_cvt_pkrtz(v[6], v[7]);
                int slot = t4 ^ (w & 7);
                *(uint4*)&s_srch[w * 64 + slot * 8] = qq.u;
            }
            __syncthreads();
#pragma unroll
            for (int wi = 0; wi < 2; ++wi) {
                int wrow = (2 * q + wi) * 16 + r;
#pragma unroll
                for (int ksl = 0; ksl < 2; ++ksl) {
                    int slot = (ksl * 4 + g) ^ (wrow & 7);
                    a[row][wi][chalf * 2 + ksl] = *(const f16x8*)&s_srch[wrow * 64 + slot * 8];
                }
            }
            asm volatile("s_waitcnt lgkmcnt(0)" ::: "memory");
            __syncthreads();   // frags in regs everywhere before re-pack / s_o overlay
        }
    }
    // (last __syncthreads drained vmcnt(0): chunks 0,1 landed, FIFO empty)

    float* outb = out + (size_t)b * (NKD * NKD) * (HH * WW) + (size_t)h0 * WW;
    float* so = s_o + q * (32 * 50);

    // vmcnt FIFO per wave: 3 loads/stage(t+2, issued after barrier), stores/epilogue:
    //   d=0: phl0 -> 3 stores, phl1..10 -> 6.  d=1: phl0..9 -> 6, phl10 -> 3.
    // cc0: need L(t)@cc2 prev ph; newer: L(t+1)@cc3 + S_prev -> 3+S_prev.
    // cc1: need L(t)@cc3 prev ph; newer: S_prev + L@cc0 -> 3+S_prev.
    // cc2/cc3: need L@cc0/cc1 same ph; newer: one stage -> 3; last ph: t=42 -> 3, t=43 -> 0.
    // phl==0: needed loads pre-drained; any count safe.
    for (int phl = 0; phl < 11; ++phl) {
        int ph_g = d * 11 + phl;
        int row0_on = (ph_g <= 20);
        int row1_on = (ph_g >= 1);

        f32x4 acc[2][2][3];   // [row][wi][pj]
#pragma unroll
        for (int row = 0; row < 2; ++row)
#pragma unroll
            for (int wi = 0; wi < 2; ++wi)
#pragma unroll
                for (int pj = 0; pj < 3; ++pj)
#pragma unroll
                    for (int j = 0; j < 4; ++j) acc[row][wi][pj][j] = 0.f;

#pragma unroll
        for (int cc = 0; cc < 4; ++cc) {
            int t = phl * 4 + cc;
            if (cc < 2) {
                if (d == 0 && phl == 1) asm volatile("s_waitcnt vmcnt(6)" ::: "memory");
                else                    asm volatile("s_waitcnt vmcnt(9)" ::: "memory");
            } else if (t == 43) {
                asm volatile("s_waitcnt vmcnt(0)" ::: "memory");
            } else {
                asm volatile("s_waitcnt vmcnt(3)" ::: "memory");
            }
            __builtin_amdgcn_s_barrier();
            __builtin_amdgcn_sched_barrier(0);
            if (t + 2 < 44) stage(t + 2);

            const char* buf = s_ring + (size_t)(t & 3) * CH_BYTES;
            f16x8 bfr[4];
#pragma unroll
            for (int pi = 0; pi < 4; ++pi)
                bfr[pi] = *(const f16x8*)(buf + ((2 * q + pi) * 16 + r) * 80 + g * 16);

            if (row0_on) {
#pragma unroll
                for (int wi = 0; wi < 2; ++wi)
#pragma unroll
                    for (int pj = 0; pj < 3; ++pj)
                        acc[0][wi][pj] = __builtin_amdgcn_mfma_f32_16x16x32_f16(
                            a[0][wi][cc], bfr[wi + pj], acc[0][wi][pj], 0, 0, 0);
            }
            if (row1_on) {
#pragma unroll
                for (int wi = 0; wi < 2; ++wi)
#pragma unroll
                    for (int pj = 0; pj < 3; ++pj)
                        acc[1][wi][pj] = __builtin_amdgcn_mfma_f32_16x16x32_f16(
                            a[1][wi][cc], bfr[wi + pj], acc[1][wi][pj], 0, 0, 0);
            }
        }

        // ---- staggered epilogues: row0 dy=ph_g, row1 dy=ph_g-1 (s_o wave-private) ----
#pragma unroll
        for (int row = 0; row < 2; ++row) {
            int dy = ph_g - row;
            if ((row == 0 && !row0_on) || (row == 1 && !row1_on)) continue;
#pragma unroll
            for (int wi = 0; wi < 2; ++wi)
#pragma unroll
                for (int pj = 0; pj < 3; ++pj)
#pragma unroll
                    for (int j = 0; j < 4; ++j)
                        so[(wi * 16 + 4 * g + j) * 50 + pj * 16 + r] = acc[row][wi][pj][j];
            asm volatile("s_waitcnt lgkmcnt(0)" ::: "memory");
            __builtin_amdgcn_sched_barrier(0);
            float* op = outb + (size_t)row * WW + (size_t)dy * NKD * (HH * WW);
#pragma unroll
            for (int k = 0; k < 3; ++k) {     // exactly 3 store instrs per wave
                int f = k * 64 + lane;
                if (f < NKD * 8) {
                    int dx = f >> 3, w4l = (f & 7) << 2;   // local w in wave's 32-w slab
                    float4 v;
                    v.x = so[(w4l + 0) * 50 + ((w4l + 0) & 15) + dx];
                    v.y = so[(w4l + 1) * 50 + ((w4l + 1) & 15) + dx];
                    v.z = so[(w4l + 2) * 50 + ((w4l + 2) & 15) + dx];
                    v.w = so[(w4l + 3) * 50 + ((w4l + 3) & 15) + dx];
                    *(float4*)&op[(size_t)dx * (HH * WW) + q * 32 + w4l] = v;
                }
            }
            asm volatile("s_waitcnt lgkmcnt(0)" ::: "memory");  // reads done before row1 rewrites
        }
    }
}

extern "C" void kernel_launch(void* const* d_in, const int* in_sizes, int n_in,
                              void* d_out, int out_size, void* d_ws, size_t ws_size,
                              hipStream_t stream) {
    const float* in = (const float*)d_in[0];
    float* out = (float*)d_out;
    __fp16* img_tgt = (__fp16*)d_ws;

    hipLaunchKernelGGL(pack_tgt, dim3(4 * HPAD), dim3(256), 0, stream, in, img_tgt);
    hipLaunchKernelGGL(corr_mfma, dim3(512), dim3(256), 0, stream, in, img_tgt, out);
}

// Round 14
// 54.610 us; speedup vs baseline: 1.6297x; 1.0462x over previous
//
#include <hip/hip_runtime.h>

#define HH 128
#define WW 128
#define CCH 128
#define NKD 21
#define RAD 10
#define HPAD 148                 // tgt images per b (hp = h+dy, 0..147)
#define ROWH 40                  // halves per row (32c + 8 pad) = 80B
#define CH_HALVES (148 * ROWH)   // 5920 halves per chunk (148 p-rows)
#define CH_BYTES  (CH_HALVES * 2)        // 11840 B
#define IMG_HALVES (4 * CH_HALVES)       // 23680 halves per (b,hp) = 47360 B

typedef _Float16 f16x8 __attribute__((ext_vector_type(8)));
typedef float    f32x4 __attribute__((ext_vector_type(4)));
typedef __fp16   h2f   __attribute__((ext_vector_type(2)));

union PK { uint4 u; h2f h[4]; };

// ------- kernel 1: pack tgt -> f16 image [hp][chunk(32c)][p(148)][40 halves], zero-padded -------
__global__ __launch_bounds__(256)
void pack_tgt(const float* __restrict__ in, __fp16* __restrict__ img) {
    int n = blockIdx.x;                 // 592: b*148 + i (tgt row = i-10)
    int b = n / HPAD, i = n - b * HPAD;
    int tid = threadIdx.x;
    uint4* gi = (uint4*)(img + (size_t)n * IMG_HALVES);
    if (i < RAD || i > 137) {           // h out of range -> all-zero image (2960 uint4)
        uint4 z = make_uint4(0, 0, 0, 0);
#pragma unroll
        for (int k = 0; k < 11; ++k) gi[k * 256 + tid] = z;
        if (tid < 144) gi[11 * 256 + tid] = z;
        return;
    }
    __shared__ __align__(16) char sraw[4 * CH_BYTES];   // 46.25KB
    {   // zero-fill (covers p<10, p>137 pad rows and the 8-half row tail)
        uint4 z = make_uint4(0, 0, 0, 0);
        uint4* sp = (uint4*)sraw;
#pragma unroll
        for (int k = 0; k < 11; ++k) sp[k * 256 + tid] = z;
        if (tid < 144) sp[11 * 256 + tid] = z;
    }
    __syncthreads();
    const float* tg = in + (size_t)(b * 2 + 1) * CCH * HH * WW + (size_t)(i - RAD) * WW;
    int w = tid & 127, half = tid >> 7;
    int p = w + RAD;                    // 10..137
#pragma unroll
    for (int c2 = 0; c2 < 2; ++c2) {
        int cc = half * 2 + c2;         // chunk 0..3 (32 channels each)
#pragma unroll
        for (int g = 0; g < 4; ++g) {   // slot g = halves c_local g*8..g*8+7
            float v[8];
#pragma unroll
            for (int j = 0; j < 8; ++j)
                v[j] = tg[(size_t)(cc * 32 + g * 8 + j) * (HH * WW) + w];
            PK q;
            q.h[0] = __builtin_amdgcn_cvt_pkrtz(v[0], v[1]);
            q.h[1] = __builtin_amdgcn_cvt_pkrtz(v[2], v[3]);
            q.h[2] = __builtin_amdgcn_cvt_pkrtz(v[4], v[5]);
            q.h[3] = __builtin_amdgcn_cvt_pkrtz(v[6], v[7]);
            *(uint4*)(sraw + (size_t)cc * CH_BYTES + p * 80 + g * 16) = q.u;
        }
    }
    __syncthreads();
    const uint4* si = (const uint4*)sraw;
#pragma unroll
    for (int k = 0; k < 11; ++k) gi[k * 256 + tid] = si[k * 256 + tid];
    if (tid < 144) gi[11 * 256 + tid] = si[11 * 256 + tid];
}

// -------- kernel 2: 2-row block, dy-split, BARRIER-FREE main loop --------
// B-fragments read directly from the packed global image (L2/L3-resident) into a
// 2-deep register ring; no LDS staging, no s_barrier, no manual vmcnt in the loop.
// MFMA: a (w-rows) FIRST, bfr (p-cols) SECOND -> acc rows=w(4g+j), cols=p(r).
__global__ __launch_bounds__(256, 2)
void corr_mfma(const float* __restrict__ in, const __fp16* __restrict__ img_tgt,
               float* __restrict__ out) {
    int n = blockIdx.x;                 // 512
    int xcd = n & 7, idx = n >> 3;
    int u = xcd * 64 + idx;             // A/B pairs adjacent on one XCD
    int d = u & 1;                      // dy-split half
    int hpair = u >> 1;                 // 0..255
    int b = hpair >> 6;                 // 0..3
    int h0 = (hpair & 63) << 1;         // even row base

    // LDS: s_srch (16KB, prologue) overlaid by s_o (25.6KB, wave-private slabs)
    __shared__ __align__(16) char smem[25600];
    __fp16* s_srch = (__fp16*)smem;
    float*  s_o    = (float*)smem;

    int tid = threadIdx.x;
    int q = tid >> 6, lane = tid & 63, r = lane & 15, g = lane >> 4;

    const char* tgbc = (const char*)(img_tgt + (size_t)(b * HPAD) * IMG_HALVES);
    const int hbase = h0 + d * 11;      // hp = hbase + (t>>2), max 147

    // ---- pack src rows via 16KB c-half buffer; A-frags to regs ----
    f16x8 a[2][2][4];   // [row][wi][cc-group]
#pragma unroll
    for (int row = 0; row < 2; ++row) {
        const float* src = in + (size_t)(b * 2) * CCH * HH * WW + (size_t)(h0 + row) * WW;
        const float sc = 1.f / 128.f;
        int w = tid & 127, hb = tid >> 7;
#pragma unroll
        for (int chalf = 0; chalf < 2; ++chalf) {
#pragma unroll
            for (int i4 = 0; i4 < 4; ++i4) {
                int t4 = hb * 4 + i4;           // c-block within half, 0..7
                float v[8];
#pragma unroll
                for (int j = 0; j < 8; ++j)
                    v[j] = src[(size_t)(chalf * 64 + t4 * 8 + j) * (HH * WW) + w] * sc;
                PK qq;
                qq.h[0] = __builtin_amdgcn_cvt_pkrtz(v[0], v[1]);
                qq.h[1] = __builtin_amdgcn_cvt_pkrtz(v[2], v[3]);
                qq.h[2] = __builtin_amdgcn_cvt_pkrtz(v[4], v[5]);
                qq.h[3] = __builtin_amdgcn_cvt_pkrtz(v[6], v[7]);
                int slot = t4 ^ (w & 7);
                *(uint4*)&s_srch[w * 64 + slot * 8] = qq.u;
            }
            __syncthreads();
#pragma unroll
            for (int wi = 0; wi < 2; ++wi) {
                int wrow = (2 * q + wi) * 16 + r;
#pragma unroll
                for (int ksl = 0; ksl < 2; ++ksl) {
                    int slot = (ksl * 4 + g) ^ (wrow & 7);
                    a[row][wi][chalf * 2 + ksl] = *(const f16x8*)&s_srch[wrow * 64 + slot * 8];
                }
            }
            asm volatile("s_waitcnt lgkmcnt(0)" ::: "memory");
            __syncthreads();   // frags in regs everywhere before re-pack / s_o overlay
        }
    }

    // ---- static per-thread byte offsets within a chunk (clamped band rows) ----
    // prow>147 would read past the image; clamp to 147 — those lanes feed only
    // acc columns p>=148, which the epilogue never stores (max stored p = 147).
    int off[4];
#pragma unroll
    for (int pi = 0; pi < 4; ++pi) {
        int prow = (2 * q + pi) * 16 + r;
        if (prow > 147) prow = 147;
        off[pi] = prow * 80 + g * 16;
    }

    float* outb = out + (size_t)b * (NKD * NKD) * (HH * WW) + (size_t)h0 * WW;
    float* so = s_o + q * (32 * 50);

    // 2-deep register prefetch ring over 44 chunks; chunk t lives in buf[t&1].
    uint4 buf[2][4];
    {
        const char* c0 = tgbc + ((size_t)hbase * 4 + 0) * CH_BYTES;
        const char* c1 = tgbc + ((size_t)hbase * 4 + 1) * CH_BYTES;
#pragma unroll
        for (int pi = 0; pi < 4; ++pi) buf[0][pi] = *(const uint4*)(c0 + off[pi]);
#pragma unroll
        for (int pi = 0; pi < 4; ++pi) buf[1][pi] = *(const uint4*)(c1 + off[pi]);
    }

    for (int phl = 0; phl < 11; ++phl) {
        int ph_g = d * 11 + phl;
        int row0_on = (ph_g <= 20);
        int row1_on = (ph_g >= 1);

        f32x4 acc[2][2][3];   // [row][wi][pj]
#pragma unroll
        for (int row = 0; row < 2; ++row)
#pragma unroll
            for (int wi = 0; wi < 2; ++wi)
#pragma unroll
                for (int pj = 0; pj < 3; ++pj)
#pragma unroll
                    for (int j = 0; j < 4; ++j) acc[row][wi][pj][j] = 0.f;

#pragma unroll
        for (int cc = 0; cc < 4; ++cc) {
            int t = phl * 4 + cc;
            f16x8 bfr[4];
#pragma unroll
            for (int pi = 0; pi < 4; ++pi)
                bfr[pi] = __builtin_bit_cast(f16x8, buf[cc & 1][pi]);

            if (t + 2 < 44) {   // prefetch chunk t+2 into the slot just consumed
                const char* cp = tgbc
                    + ((size_t)(hbase + ((t + 2) >> 2)) * 4 + ((t + 2) & 3)) * CH_BYTES;
#pragma unroll
                for (int pi = 0; pi < 4; ++pi)
                    buf[cc & 1][pi] = *(const uint4*)(cp + off[pi]);
            }

            if (row0_on) {
#pragma unroll
                for (int wi = 0; wi < 2; ++wi)
#pragma unroll
                    for (int pj = 0; pj < 3; ++pj)
                        acc[0][wi][pj] = __builtin_amdgcn_mfma_f32_16x16x32_f16(
                            a[0][wi][cc], bfr[wi + pj], acc[0][wi][pj], 0, 0, 0);
            }
            if (row1_on) {
#pragma unroll
                for (int wi = 0; wi < 2; ++wi)
#pragma unroll
                    for (int pj = 0; pj < 3; ++pj)
                        acc[1][wi][pj] = __builtin_amdgcn_mfma_f32_16x16x32_f16(
                            a[1][wi][cc], bfr[wi + pj], acc[1][wi][pj], 0, 0, 0);
            }
        }

        // ---- staggered epilogues: row0 dy=ph_g, row1 dy=ph_g-1 (s_o wave-private) ----
#pragma unroll
        for (int row = 0; row < 2; ++row) {
            int dy = ph_g - row;
            if ((row == 0 && !row0_on) || (row == 1 && !row1_on)) continue;
#pragma unroll
            for (int wi = 0; wi < 2; ++wi)
#pragma unroll
                for (int pj = 0; pj < 3; ++pj)
#pragma unroll
                    for (int j = 0; j < 4; ++j)
                        so[(wi * 16 + 4 * g + j) * 50 + pj * 16 + r] = acc[row][wi][pj][j];
            asm volatile("s_waitcnt lgkmcnt(0)" ::: "memory");
            __builtin_amdgcn_sched_barrier(0);
            float* op = outb + (size_t)row * WW + (size_t)dy * NKD * (HH * WW);
#pragma unroll
            for (int k = 0; k < 3; ++k) {
                int f = k * 64 + lane;
                if (f < NKD * 8) {
                    int dx = f >> 3, w4l = (f & 7) << 2;   // local w in wave's 32-w slab
                    float4 v;
                    v.x = so[(w4l + 0) * 50 + ((w4l + 0) & 15) + dx];
                    v.y = so[(w4l + 1) * 50 + ((w4l + 1) & 15) + dx];
                    v.z = so[(w4l + 2) * 50 + ((w4l + 2) & 15) + dx];
                    v.w = so[(w4l + 3) * 50 + ((w4l + 3) & 15) + dx];
                    *(float4*)&op[(size_t)dx * (HH * WW) + q * 32 + w4l] = v;
                }
            }
            asm volatile("s_waitcnt lgkmcnt(0)" ::: "memory");  // reads done before row1 rewrites
        }
    }
}

extern "C" void kernel_launch(void* const* d_in, const int* in_sizes, int n_in,
                              void* d_out, int out_size, void* d_ws, size_t ws_size,
                              hipStream_t stream) {
    const float* in = (const float*)d_in[0];
    float* out = (float*)d_out;
    __fp16* img_tgt = (__fp16*)d_ws;

    hipLaunchKernelGGL(pack_tgt, dim3(4 * HPAD), dim3(256), 0, stream, in, img_tgt);
    hipLaunchKernelGGL(corr_mfma, dim3(512), dim3(256), 0, stream, in, img_tgt, out);
}